// Round 16
// baseline (313.259 us; speedup 1.0000x reference)
//
#include <hip/hip_runtime.h>
#include <hip/hip_bf16.h>

namespace {
constexpr int Bn = 8, Cn = 256, Kn = 128, Hn = 112, Wn = 112;
constexpr int Pn = Hn * Wn;                          // 12544 = 98*128
constexpr long long NOUT = (long long)Bn * Kn * Pn;  // 12845056 per output tensor

typedef __attribute__((ext_vector_type(8))) short bf16x8;
typedef __attribute__((ext_vector_type(4))) float f32x4;
typedef __attribute__((ext_vector_type(2))) float f32x2;

__device__ inline unsigned short f2bf(float f) {
  __hip_bfloat16 h = __float2bfloat16(f);  // RNE
  return __builtin_bit_cast(unsigned short, h);
}
__device__ inline unsigned int pack2bf(float a, float b) {
  return (unsigned int)f2bf(a) | ((unsigned int)f2bf(b) << 16);
}
__device__ inline float bf2f(unsigned short u) {
  return __bfloat162float(__builtin_bit_cast(__hip_bfloat16, u));
}
}

// lcQ packed for vectorized B-frag loads (uint4 per lane per (s,ks)).
__global__ __launch_bounds__(256) void prep_lcQ(const float* __restrict__ lc,
                                                unsigned int* __restrict__ lcQ) {
  int idx = blockIdx.x * 256 + threadIdx.x;  // 64 blocks -> 16384
  int r = idx & 3;
  int l15 = (idx >> 2) & 15;
  int l4 = (idx >> 6) & 3;
  int ks = (idx >> 8) & 7;
  int s = idx >> 11;
  int c2 = s * 16 + l4 * 4 + r;
  int k = ks * 16 + l15;
  lcQ[idx] = pack2bf(lc[k * Cn + 2 * c2], lc[k * Cn + 2 * c2 + 1]);
}

// comb[b][k][p] (bf16) = sum_c lc[k][c]*x[b][c][p]. 128p x 128k block tile,
// 4 waves (32p x 128k each), LDS double-buffered x staging with async-split.
__global__ __launch_bounds__(256) void gemm_mfma(const float* __restrict__ x,
                                                 const uint4* __restrict__ lcQ4,
                                                 unsigned short* __restrict__ combh) {
  __shared__ __align__(16) float xs[2][32][128];  // 2 x 16 KB
  const int tid = threadIdx.x;
  const int wid = tid >> 6;
  const int lane = tid & 63;
  const int l15 = lane & 15, l4 = lane >> 4;
  const int b = blockIdx.x / 98;
  const int p0 = (blockIdx.x % 98) * 128;
  const float* xb = x + (size_t)b * Cn * Pn + p0;

  // staging map: 1024 float4/step; thread takes fidx = q*256+tid, q=0..3:
  // row = fidx>>5, col = (fidx&31)*4
  int srow[4], scol[4];
#pragma unroll
  for (int q = 0; q < 4; ++q) {
    int fidx = q * 256 + tid;
    srow[q] = fidx >> 5;
    scol[q] = (fidx & 31) * 4;
  }

  f32x4 acc[8][2];
#pragma unroll
  for (int ks = 0; ks < 8; ++ks)
#pragma unroll
    for (int ps = 0; ps < 2; ++ps) acc[ks][ps] = (f32x4)(0.f);

  // prologue: stage step 0
#pragma unroll
  for (int q = 0; q < 4; ++q) {
    float4 v = *reinterpret_cast<const float4*>(xb + (size_t)srow[q] * Pn + scol[q]);
    *reinterpret_cast<float4*>(&xs[0][srow[q]][scol[q]]) = v;
  }
  __syncthreads();

  for (int s = 0; s < 8; ++s) {
    const int cur = s & 1;
    // async-split: issue next step's loads before compute
    float4 nv[4];
    if (s < 7) {
      const float* g = xb + (size_t)(32 * (s + 1)) * Pn;
#pragma unroll
      for (int q = 0; q < 4; ++q)
        nv[q] = *reinterpret_cast<const float4*>(g + (size_t)srow[q] * Pn + scol[q]);
    }

    // A-frags from LDS: lane holds A[p = p0+wid*32+ps*16+l15][c = 32s+l4*8+j]
    union { unsigned int u[4]; bf16x8 vv; } au[2];
#pragma unroll
    for (int ps = 0; ps < 2; ++ps) {
      float v[8];
#pragma unroll
      for (int j = 0; j < 8; ++j) v[j] = xs[cur][l4 * 8 + j][wid * 32 + ps * 16 + l15];
#pragma unroll
      for (int r = 0; r < 4; ++r) au[ps].u[r] = pack2bf(v[2 * r], v[2 * r + 1]);
    }
#pragma unroll
    for (int ks = 0; ks < 8; ++ks) {
      union { uint4 q; bf16x8 vv; } bu;
      bu.q = lcQ4[((s * 8 + ks) * 4 + l4) * 16 + l15];
#pragma unroll
      for (int ps = 0; ps < 2; ++ps)
        acc[ks][ps] = __builtin_amdgcn_mfma_f32_16x16x32_bf16(au[ps].vv, bu.vv, acc[ks][ps], 0, 0, 0);
    }

    if (s < 7) {
#pragma unroll
      for (int q = 0; q < 4; ++q)
        *reinterpret_cast<float4*>(&xs[cur ^ 1][srow[q]][scol[q]]) = nv[q];
    }
    __syncthreads();
  }

  // D: col(l15)=k, row(l4*4+reg)=p
#pragma unroll
  for (int ks = 0; ks < 8; ++ks) {
    const size_t krow = ((size_t)b * Kn + ks * 16 + l15) * Pn;
#pragma unroll
    for (int ps = 0; ps < 2; ++ps) {
      const int p = p0 + wid * 32 + ps * 16 + l4 * 4;
      uint2 st;
      st.x = pack2bf(acc[ks][ps][0], acc[ks][ps][1]);
      st.y = pack2bf(acc[ks][ps][2], acc[ks][ps][3]);
      *reinterpret_cast<uint2*>(combh + krow + p) = st;
    }
  }
}

// One block per (b,k): stage image in LDS, gather from LDS, 2 px/thread.
__global__ __launch_bounds__(256) void sample_lds(const unsigned short* __restrict__ comb,
                                                  const float* __restrict__ geo,
                                                  const float* __restrict__ boxp,
                                                  float* __restrict__ outF,
                                                  float* __restrict__ outW,
                                                  float* __restrict__ outB) {
  __shared__ __align__(16) unsigned short img[Pn];  // 25088 B
  const int bx = blockIdx.x;  // b*128 + k
  const int k = bx & 127;
  const int tid = threadIdx.x;

  {
    const uint4* src = reinterpret_cast<const uint4*>(comb + (size_t)bx * Pn);
    uint4* dst = reinterpret_cast<uint4*>(img);
    for (int i = tid; i < Pn / 8; i += 256) dst[i] = src[i];
  }
  __syncthreads();

  const float* g = geo + k * 6;
  const float* t = boxp + k * 6;
  const float g0 = g[0], g1 = g[1], g2 = g[2], g3 = g[3], g4 = g[4], g5 = g[5];
  const float t0 = t[0], t1 = t[1], t2 = t[2], t3 = t[3], t4 = t[4], t5 = t[5];
  const size_t obase = (size_t)bx * Pn;

  for (int i = 0; i < 25; ++i) {
    const int idx = tid + i * 256;
    if (idx >= Pn / 2) break;
    const int p = 2 * idx;
    const int h = idx / 56;            // == p / 112
    const int w0 = p - h * Wn;
    const float yn = (2.f * h + 1.f) / (float)Hn - 1.f;

    float vv[2], bb[2];
#pragma unroll
    for (int e = 0; e < 2; ++e) {
      const int w = w0 + e;
      const float xn = (2.f * w + 1.f) / (float)Wn - 1.f;  // bit-identical to ref

      float ix = ((g0 * xn + g1 * yn + g2 + 1.f) * Wn - 1.f) * 0.5f;
      float iy = ((g3 * xn + g4 * yn + g5 + 1.f) * Hn - 1.f) * 0.5f;
      float x0f = floorf(ix), y0f = floorf(iy);
      float wx1 = ix - x0f, wx0 = 1.f - wx1;
      float wy1 = iy - y0f, wy0 = 1.f - wy1;
      float vx0 = (x0f >= 0.f && x0f <= (float)(Wn - 1)) ? 1.f : 0.f;
      float vx1 = (x0f + 1.f >= 0.f && x0f + 1.f <= (float)(Wn - 1)) ? 1.f : 0.f;
      float vy0 = (y0f >= 0.f && y0f <= (float)(Hn - 1)) ? 1.f : 0.f;
      float vy1 = (y0f + 1.f >= 0.f && y0f + 1.f <= (float)(Hn - 1)) ? 1.f : 0.f;
      int x0i = (int)fminf(fmaxf(x0f, 0.f), (float)(Wn - 1));
      int x1i = (int)fminf(fmaxf(x0f + 1.f, 0.f), (float)(Wn - 1));
      int y0i = (int)fminf(fmaxf(y0f, 0.f), (float)(Hn - 1));
      int y1i = (int)fminf(fmaxf(y0f + 1.f, 0.f), (float)(Hn - 1));
      float w00 = wx0 * wy0 * vx0 * vy0;
      float w01 = wx1 * wy0 * vx1 * vy0;
      float w10 = wx0 * wy1 * vx0 * vy1;
      float w11 = wx1 * wy1 * vx1 * vy1;
      vv[e] = w00 * bf2f(img[y0i * Wn + x0i]) + w01 * bf2f(img[y0i * Wn + x1i]) +
              w10 * bf2f(img[y1i * Wn + x0i]) + w11 * bf2f(img[y1i * Wn + x1i]);

      float bix = ((t0 * xn + t1 * yn + t2 + 1.f) * Wn - 1.f) * 0.5f;
      float biy = ((t3 * xn + t4 * yn + t5 + 1.f) * Hn - 1.f) * 0.5f;
      float bx0 = floorf(bix), by0 = floorf(biy);
      float bwx1 = bix - bx0, bwx0 = 1.f - bwx1;
      float bwy1 = biy - by0, bwy0 = 1.f - bwy1;
      float bvx0 = (bx0 >= 0.f && bx0 <= (float)(Wn - 1)) ? 1.f : 0.f;
      float bvx1 = (bx0 + 1.f >= 0.f && bx0 + 1.f <= (float)(Wn - 1)) ? 1.f : 0.f;
      float bvy0 = (by0 >= 0.f && by0 <= (float)(Hn - 1)) ? 1.f : 0.f;
      float bvy1 = (by0 + 1.f >= 0.f && by0 + 1.f <= (float)(Hn - 1)) ? 1.f : 0.f;
      bb[e] = bwx0 * bwy0 * bvx0 * bvy0 + bwx1 * bwy0 * bvx1 * bvy0 +
              bwx0 * bwy1 * bvx0 * bvy1 + bwx1 * bwy1 * bvx1 * bvy1;
    }

    const size_t o = obase + p;
    f32x2 wv; wv.x = vv[0]; wv.y = vv[1];
    f32x2 bv; bv.x = bb[0]; bv.y = bb[1];
    f32x2 fv; fv.x = vv[0] * bb[0]; fv.y = vv[1] * bb[1];
    __builtin_nontemporal_store(wv, reinterpret_cast<f32x2*>(&outW[o]));
    __builtin_nontemporal_store(bv, reinterpret_cast<f32x2*>(&outB[o]));
    __builtin_nontemporal_store(fv, reinterpret_cast<f32x2*>(&outF[o]));
  }
}

extern "C" void kernel_launch(void* const* d_in, const int* in_sizes, int n_in,
                              void* d_out, int out_size, void* d_ws, size_t ws_size,
                              hipStream_t stream) {
  (void)in_sizes; (void)n_in; (void)out_size;
  const float* x = (const float*)d_in[0];
  const float* lc = (const float*)d_in[1];
  const float* geo = (const float*)d_in[2];
  const float* boxp = (const float*)d_in[3];
  float* outF = (float*)d_out;
  float* outW = outF + NOUT;
  float* outB = outW + NOUT;

  unsigned int* lcQ = (unsigned int*)outB;  // consumed by gemm before sampler writes

  const size_t comb_bytes = (size_t)NOUT * sizeof(unsigned short);  // 25.7 MB
  const bool use_ws = ws_size >= comb_bytes;
  unsigned short* combh = use_ws ? (unsigned short*)d_ws : (unsigned short*)outF;

  prep_lcQ<<<64, 256, 0, stream>>>(lc, lcQ);
  gemm_mfma<<<Bn * (Pn / 128), 256, 0, stream>>>(x, (const uint4*)lcQ, combh);
  sample_lds<<<Bn * Kn, 256, 0, stream>>>(combh, geo, boxp, outF, outW, outB);
}

// Round 18
// 268.686 us; speedup vs baseline: 1.1659x; 1.1659x over previous
//
#include <hip/hip_runtime.h>
#include <hip/hip_bf16.h>

namespace {
constexpr int Bn = 8, Cn = 256, Kn = 128, Hn = 112, Wn = 112;
constexpr int Pn = Hn * Wn;                          // 12544 = 98*128
constexpr long long NOUT = (long long)Bn * Kn * Pn;  // 12845056 per output tensor

typedef __attribute__((ext_vector_type(8))) short bf16x8;
typedef __attribute__((ext_vector_type(4))) float f32x4;
typedef __attribute__((ext_vector_type(2))) float f32x2;

__device__ inline unsigned short f2bf(float f) {
  __hip_bfloat16 h = __float2bfloat16(f);  // RNE
  return __builtin_bit_cast(unsigned short, h);
}
__device__ inline unsigned int pack2bf(float a, float b) {
  return (unsigned int)f2bf(a) | ((unsigned int)f2bf(b) << 16);
}
__device__ inline float bf2f(unsigned short u) {
  return __bfloat162float(__builtin_bit_cast(__hip_bfloat16, u));
}
}

// lcQ packed for vectorized B-frag loads (uint4 per lane per (s,ks)).
__global__ __launch_bounds__(256) void prep_lcQ(const float* __restrict__ lc,
                                                unsigned int* __restrict__ lcQ) {
  int idx = blockIdx.x * 256 + threadIdx.x;  // 64 blocks -> 16384
  int r = idx & 3;
  int l15 = (idx >> 2) & 15;
  int l4 = (idx >> 6) & 3;
  int ks = (idx >> 8) & 7;
  int s = idx >> 11;
  int c2 = s * 16 + l4 * 4 + r;
  int k = ks * 16 + l15;
  lcQ[idx] = pack2bf(lc[k * Cn + 2 * c2], lc[k * Cn + 2 * c2 + 1]);
}

// comb = lc @ x via mfma. R16 profile: reg-staged version 95% stalled
// (MfmaUtil 2.4, VALU 3.3, 770 GB/s). Fix: global_load_lds width=16 staging,
// double-buffered; next tile's loads issued BEFORE current compute, drained
// only at the barrier (m97 structure). LDS dest is wave-uniform base+lane*16:
// wave w, call n covers rows {2*(w*4+n), +1} of the [32][128] fp32 tile.
__global__ __launch_bounds__(256) void gemm_mfma(const float* __restrict__ x,
                                                 const uint4* __restrict__ lcQ4,
                                                 unsigned short* __restrict__ combh) {
  __shared__ __align__(16) float xs[2][32][128];  // 2 x 16 KB
  const int tid = threadIdx.x;
  const int wid = tid >> 6;
  const int lane = tid & 63;
  const int l15 = lane & 15, l4 = lane >> 4;
  const int b = blockIdx.x / 98;
  const int p0 = (blockIdx.x % 98) * 128;
  const float* xb = x + (size_t)b * Cn * Pn + p0;

  // per-lane source column for global_load_lds: row += lane>>5, col = (lane&31)*4
  const int lrow = lane >> 5;
  const int lcol = (lane & 31) * 4;

  f32x4 acc[8][2];
#pragma unroll
  for (int ks = 0; ks < 8; ++ks)
#pragma unroll
    for (int ps = 0; ps < 2; ++ps) acc[ks][ps] = (f32x4)(0.f);

  typedef __attribute__((address_space(1))) const unsigned int guint;
  typedef __attribute__((address_space(3))) unsigned int luint;

  // prologue: stage step 0 into buf 0
#pragma unroll
  for (int n = 0; n < 4; ++n) {
    const int seg = wid * 4 + n;
    const float* gsrc = xb + (size_t)(2 * seg + lrow) * Pn + lcol;
    __builtin_amdgcn_global_load_lds((guint*)gsrc, (luint*)&xs[0][2 * seg][0], 16, 0, 0);
  }
  __syncthreads();

  for (int s = 0; s < 8; ++s) {
    const int cur = s & 1;
    // issue next tile's loads FIRST (in flight across this step's compute)
    if (s < 7) {
#pragma unroll
      for (int n = 0; n < 4; ++n) {
        const int seg = wid * 4 + n;
        const float* gsrc = xb + (size_t)(32 * (s + 1) + 2 * seg + lrow) * Pn + lcol;
        __builtin_amdgcn_global_load_lds((guint*)gsrc, (luint*)&xs[cur ^ 1][2 * seg][0], 16, 0, 0);
      }
    }

    // A-frags from LDS: lane holds A[p = p0+wid*32+ps*16+l15][c = 32s+l4*8+j]
    union { unsigned int u[4]; bf16x8 vv; } au[2];
#pragma unroll
    for (int ps = 0; ps < 2; ++ps) {
      float v[8];
#pragma unroll
      for (int j = 0; j < 8; ++j) v[j] = xs[cur][l4 * 8 + j][wid * 32 + ps * 16 + l15];
#pragma unroll
      for (int r = 0; r < 4; ++r) au[ps].u[r] = pack2bf(v[2 * r], v[2 * r + 1]);
    }
#pragma unroll
    for (int ks = 0; ks < 8; ++ks) {
      union { uint4 q; bf16x8 vv; } bu;
      bu.q = lcQ4[((s * 8 + ks) * 4 + l4) * 16 + l15];
#pragma unroll
      for (int ps = 0; ps < 2; ++ps)
        acc[ks][ps] = __builtin_amdgcn_mfma_f32_16x16x32_bf16(au[ps].vv, bu.vv, acc[ks][ps], 0, 0, 0);
    }
    __syncthreads();  // drains vmcnt (next buf ready) + lgkm
  }

  // D: col(l15)=k, row(l4*4+reg)=p
#pragma unroll
  for (int ks = 0; ks < 8; ++ks) {
    const size_t krow = ((size_t)b * Kn + ks * 16 + l15) * Pn;
#pragma unroll
    for (int ps = 0; ps < 2; ++ps) {
      const int p = p0 + wid * 32 + ps * 16 + l4 * 4;
      uint2 st;
      st.x = pack2bf(acc[ks][ps][0], acc[ks][ps][1]);
      st.y = pack2bf(acc[ks][ps][2], acc[ks][ps][3]);
      *reinterpret_cast<uint2*>(combh + krow + p) = st;
    }
  }
}

// One block per (b,k), 512 threads (8 waves -> 32 waves/CU at 4 blocks/CU):
// stage image in LDS, gather from LDS, 2 px/thread-iter.
__global__ __launch_bounds__(512) void sample_lds(const unsigned short* __restrict__ comb,
                                                  const float* __restrict__ geo,
                                                  const float* __restrict__ boxp,
                                                  float* __restrict__ outF,
                                                  float* __restrict__ outW,
                                                  float* __restrict__ outB) {
  __shared__ __align__(16) unsigned short img[Pn];  // 25088 B
  const int bx = blockIdx.x;  // b*128 + k
  const int k = bx & 127;
  const int tid = threadIdx.x;

  {
    const uint4* src = reinterpret_cast<const uint4*>(comb + (size_t)bx * Pn);
    uint4* dst = reinterpret_cast<uint4*>(img);
    for (int i = tid; i < Pn / 8; i += 512) dst[i] = src[i];
  }
  __syncthreads();

  const float* g = geo + k * 6;
  const float* t = boxp + k * 6;
  const float g0 = g[0], g1 = g[1], g2 = g[2], g3 = g[3], g4 = g[4], g5 = g[5];
  const float t0 = t[0], t1 = t[1], t2 = t[2], t3 = t[3], t4 = t[4], t5 = t[5];
  const size_t obase = (size_t)bx * Pn;

  for (int i = 0; i < 13; ++i) {
    const int idx = tid + i * 512;
    if (idx >= Pn / 2) break;
    const int p = 2 * idx;
    const int h = idx / 56;  // == p / 112
    const int w0 = p - h * Wn;
    const float yn = (2.f * h + 1.f) / (float)Hn - 1.f;

    float vv[2], bb[2];
#pragma unroll
    for (int e = 0; e < 2; ++e) {
      const int w = w0 + e;
      const float xn = (2.f * w + 1.f) / (float)Wn - 1.f;

      float ix = ((g0 * xn + g1 * yn + g2 + 1.f) * Wn - 1.f) * 0.5f;
      float iy = ((g3 * xn + g4 * yn + g5 + 1.f) * Hn - 1.f) * 0.5f;
      float x0f = floorf(ix), y0f = floorf(iy);
      float wx1 = ix - x0f, wx0 = 1.f - wx1;
      float wy1 = iy - y0f, wy0 = 1.f - wy1;
      float vx0 = (x0f >= 0.f && x0f <= (float)(Wn - 1)) ? 1.f : 0.f;
      float vx1 = (x0f + 1.f >= 0.f && x0f + 1.f <= (float)(Wn - 1)) ? 1.f : 0.f;
      float vy0 = (y0f >= 0.f && y0f <= (float)(Hn - 1)) ? 1.f : 0.f;
      float vy1 = (y0f + 1.f >= 0.f && y0f + 1.f <= (float)(Hn - 1)) ? 1.f : 0.f;
      int x0i = (int)fminf(fmaxf(x0f, 0.f), (float)(Wn - 1));
      int x1i = (int)fminf(fmaxf(x0f + 1.f, 0.f), (float)(Wn - 1));
      int y0i = (int)fminf(fmaxf(y0f, 0.f), (float)(Hn - 1));
      int y1i = (int)fminf(fmaxf(y0f + 1.f, 0.f), (float)(Hn - 1));
      float w00 = wx0 * wy0 * vx0 * vy0;
      float w01 = wx1 * wy0 * vx1 * vy0;
      float w10 = wx0 * wy1 * vx0 * vy1;
      float w11 = wx1 * wy1 * vx1 * vy1;
      vv[e] = w00 * bf2f(img[y0i * Wn + x0i]) + w01 * bf2f(img[y0i * Wn + x1i]) +
              w10 * bf2f(img[y1i * Wn + x0i]) + w11 * bf2f(img[y1i * Wn + x1i]);

      float bix = ((t0 * xn + t1 * yn + t2 + 1.f) * Wn - 1.f) * 0.5f;
      float biy = ((t3 * xn + t4 * yn + t5 + 1.f) * Hn - 1.f) * 0.5f;
      float bx0 = floorf(bix), by0 = floorf(biy);
      float bwx1 = bix - bx0, bwx0 = 1.f - bwx1;
      float bwy1 = biy - by0, bwy0 = 1.f - bwy1;
      float bvx0 = (bx0 >= 0.f && bx0 <= (float)(Wn - 1)) ? 1.f : 0.f;
      float bvx1 = (bx0 + 1.f >= 0.f && bx0 + 1.f <= (float)(Wn - 1)) ? 1.f : 0.f;
      float bvy0 = (by0 >= 0.f && by0 <= (float)(Hn - 1)) ? 1.f : 0.f;
      float bvy1 = (by0 + 1.f >= 0.f && by0 + 1.f <= (float)(Hn - 1)) ? 1.f : 0.f;
      bb[e] = bwx0 * bwy0 * bvx0 * bvy0 + bwx1 * bwy0 * bvx1 * bvy0 +
              bwx0 * bwy1 * bvx0 * bvy1 + bwx1 * bwy1 * bvx1 * bvy1;
    }

    const size_t o = obase + p;
    f32x2 wv; wv.x = vv[0]; wv.y = vv[1];
    f32x2 bv; bv.x = bb[0]; bv.y = bb[1];
    f32x2 fv; fv.x = vv[0] * bb[0]; fv.y = vv[1] * bb[1];
    __builtin_nontemporal_store(wv, reinterpret_cast<f32x2*>(&outW[o]));
    __builtin_nontemporal_store(bv, reinterpret_cast<f32x2*>(&outB[o]));
    __builtin_nontemporal_store(fv, reinterpret_cast<f32x2*>(&outF[o]));
  }
}

extern "C" void kernel_launch(void* const* d_in, const int* in_sizes, int n_in,
                              void* d_out, int out_size, void* d_ws, size_t ws_size,
                              hipStream_t stream) {
  (void)in_sizes; (void)n_in; (void)out_size;
  const float* x = (const float*)d_in[0];
  const float* lc = (const float*)d_in[1];
  const float* geo = (const float*)d_in[2];
  const float* boxp = (const float*)d_in[3];
  float* outF = (float*)d_out;
  float* outW = outF + NOUT;
  float* outB = outW + NOUT;

  unsigned int* lcQ = (unsigned int*)outB;  // consumed by gemm before sampler writes

  const size_t comb_bytes = (size_t)NOUT * sizeof(unsigned short);  // 25.7 MB
  const bool use_ws = ws_size >= comb_bytes;
  unsigned short* combh = use_ws ? (unsigned short*)d_ws : (unsigned short*)outF;

  prep_lcQ<<<64, 256, 0, stream>>>(lc, lcQ);
  gemm_mfma<<<Bn * (Pn / 128), 256, 0, stream>>>(x, (const uint4*)lcQ, combh);
  sample_lds<<<Bn * Kn, 512, 0, stream>>>(combh, geo, boxp, outF, outW, outB);
}